// Round 7
// baseline (1211.396 us; speedup 1.0000x reference)
//
#include <hip/hip_runtime.h>

// Problem constants
#define D     512
#define KK    8          // modules per batch
#define SS    4          // workspace slots
#define GB    4          // batches per block (main kernel)
#define BTOT  8192
#define SCALE 0.04419417382415922f   // 512^-0.5
#define LN_EPS 1e-5f
#define TSTR  520        // fp32 LDS row stride (floats) for t/v: 2080B, 16B-aligned
#define ASTRH 520        // bf16 LDS row stride (halfs) for A rows: 1040B, 16B-aligned

// packed-B bf16 layout, half-index: 8 consecutive k per (k-chunk, n) 16B group
#define PB(k, n) ((((k) >> 3) << 12) + ((n) << 3) + ((k) & 7))

// ---- module-scope device scratch (fully rewritten every launch) ----
__device__ int   g_flag;
__device__ float g_aq[SS * D];
__device__ __align__(16) float g_mw[D * D];            // Wq_w^T Wk_w fp32 (kaq input)
// bf16 fragment-packed B operands (typedef kept so the harness sees bf16 usage)
typedef __bf16 bf16_t;
__device__ __align__(16) unsigned short g_bv16[D * D]; // bf16(Wv_w^T):      [k][n] = Wv_w[n][k]
__device__ __align__(16) unsigned short g_mr16[D * D]; // bf16(SCALE*Mr^T):  [k][n] = SCALE*sum_i Wq_r[i][n]*Wk_r[i][k]
__device__ __align__(16) unsigned short g_mo16[D * D]; // bf16(Mo^T):        [k][n] = sum_i Wo[n][i]*Wv_r[i][k]

__device__ __forceinline__ float wred(float v){
  #pragma unroll
  for (int m = 1; m < 64; m <<= 1) v += __shfl_xor(v, m, 64);
  return v;
}
__device__ __forceinline__ unsigned short f2bf(float f){   // RNE fp32->bf16
  unsigned u = __float_as_uint(f);
  return (unsigned short)((u + 0x7FFFu + ((u >> 16) & 1u)) >> 16);
}

// ---------- KPREP: all weight-composition products in one launch ----------
// z=0: g_mw fp32; z=1: g_mr16 (SCALE folded); z=2: g_mo16; z=3: g_bv16
__global__ void kprep(const float* __restrict__ wq_w, const float* __restrict__ wk_w,
                      const float* __restrict__ wq_r, const float* __restrict__ wk_r,
                      const float* __restrict__ wo,   const float* __restrict__ wv_r,
                      const float* __restrict__ wv_w){
  const int tid = threadIdx.x, w = tid >> 6, lane = tid & 63;
  const int bx = blockIdx.x, by = blockIdx.y, z = blockIdx.z;
  if (z == 3){                                   // transpose+pack Wv_w -> bf16
    int o0 = (by * 8 + bx) * 256 + tid;          // 0..65535
    #pragma unroll
    for (int j = 0; j < 4; ++j){
      int idx = o0 + j * 65536;                  // k lane-fast: coalesced reads
      int k = idx & 511, n = idx >> 9;
      g_bv16[PB(k, n)] = f2bf(wv_w[n * D + k]);
    }
    return;
  }
  float acc[4] = {0.f, 0.f, 0.f, 0.f};
  if (z == 0){
    int dp = bx * 64 + lane;                     // coalesced over Wk_w
    int d0 = by * 16 + w * 4;
    for (int e = 0; e < D; ++e){
      float4 p = *(const float4*)(wq_w + e * D + d0);
      float  q = wk_w[e * D + dp];
      acc[0] = fmaf(p.x, q, acc[0]); acc[1] = fmaf(p.y, q, acc[1]);
      acc[2] = fmaf(p.z, q, acc[2]); acc[3] = fmaf(p.w, q, acc[3]);
    }
    #pragma unroll
    for (int j = 0; j < 4; ++j) g_mw[(d0 + j) * D + dp] = acc[j];
  } else if (z == 1){
    int n = bx * 64 + lane;                      // coalesced over Wq_r
    int k0 = by * 16 + w * 4;
    for (int i = 0; i < D; ++i){
      float4 q = *(const float4*)(wk_r + i * D + k0);
      float  p = wq_r[i * D + n];
      acc[0] = fmaf(p, q.x, acc[0]); acc[1] = fmaf(p, q.y, acc[1]);
      acc[2] = fmaf(p, q.z, acc[2]); acc[3] = fmaf(p, q.w, acc[3]);
    }
    unsigned lo = ((unsigned)f2bf(acc[1] * SCALE) << 16) | f2bf(acc[0] * SCALE);
    unsigned hi = ((unsigned)f2bf(acc[3] * SCALE) << 16) | f2bf(acc[2] * SCALE);
    *(uint2*)(g_mr16 + PB(k0, n)) = make_uint2(lo, hi);   // 8B-aligned (k0&7 in {0,4})
  } else {
    int k = bx * 64 + lane;                      // coalesced over Wv_r
    int n0 = by * 16 + w * 4;
    for (int i = 0; i < D; ++i){
      float q = wv_r[i * D + k];
      acc[0] = fmaf(wo[(n0 + 0) * D + i], q, acc[0]);
      acc[1] = fmaf(wo[(n0 + 1) * D + i], q, acc[1]);
      acc[2] = fmaf(wo[(n0 + 2) * D + i], q, acc[2]);
      acc[3] = fmaf(wo[(n0 + 3) * D + i], q, acc[3]);
    }
    #pragma unroll
    for (int j = 0; j < 4; ++j) g_mo16[PB(k, n0 + j)] = f2bf(acc[j]);
  }
}

// ---------- KAQ: g_aq[s] = slots[s] @ g_mw  + mask-layout flag ----------
// grid (4,8) x 64 threads: 32 waves spread over CUs; 8 independent FMA chains.
__global__ void kaq(const float* __restrict__ slots, const void* __restrict__ mask){
  int s = blockIdx.x, d = blockIdx.y * 64 + threadIdx.x;
  if (blockIdx.x == 0 && blockIdx.y == 0){
    __shared__ int f;
    if (threadIdx.x == 0) f = 0;
    __syncthreads();
    {
      const unsigned char* mb = (const unsigned char*)mask;
      int nz = 0;
      #pragma unroll
      for (int j = 0; j < 4; ++j){
        int wrd = threadIdx.x * 4 + j;            // first 256 mask words
        nz |= mb[wrd*4+1] | mb[wrd*4+2] | mb[wrd*4+3];
      }
      if (nz) atomicOr(&f, 1);
    }
    __syncthreads();
    if (threadIdx.x == 0) g_flag = f;
  }
  float a[8];
  #pragma unroll
  for (int j = 0; j < 8; ++j) a[j] = 0.f;
  for (int e = 0; e < D; e += 8){
    #pragma unroll
    for (int j = 0; j < 8; ++j)
      a[j] = fmaf(slots[s * D + e + j], g_mw[(e + j) * D + d], a[j]);
  }
  g_aq[s * D + d] = ((a[0]+a[1])+(a[2]+a[3])) + ((a[4]+a[5])+(a[6]+a[7]));
}

// ---------- K4: fused main, GB=4, bf16-operand GEMMs (R=8 x C=2), fp32 accum ----------
// A (h_mix/ws) in LDS as bf16: ds_read_b128 = 8 k-elements (2x fewer LDS instrs than fp32).
// B bf16-packed global (2x less L2 traffic). Unpack: hi-half of a dword IS fp32 (1 AND);
// low is 1 SHL. All accumulation fp32. bf16 error floor threshold applies (rounds 1-2).
__global__ __launch_bounds__(512, 4)
void k4_main(const float* __restrict__ hidden, const void* __restrict__ maskp,
             const float* __restrict__ slots,
             const float* __restrict__ gws, const float* __restrict__ bws,
             const float* __restrict__ gout, const float* __restrict__ bout,
             float* __restrict__ out){
  __shared__ __align__(16) char bufA[16 * TSTR * 4];        // h_mix(bf16) -> t(fp32) -> v(fp32)
  __shared__ __align__(16) unsigned short wsb[16 * ASTRH];  // ws_upd bf16 (GEMM2+3 A-operand)
  __shared__ float attw[128];                               // [bl][s][k]
  __shared__ float attr[128];                               // [bl][k][s]
  __shared__ float part1[64], part2[64];                    // LN partials [cg][row]

  unsigned short* mixH = (unsigned short*)bufA;
  float* tb = (float*)bufA;
  float* vb = (float*)bufA;

  const int tid = threadIdx.x;
  const int w = tid >> 6, lane = tid & 63;
  const int cg = w & 3;                              // col group (128 cols)
  const int rg = w >> 2;                             // row group (8 rows)
  const int col0 = (cg << 7) + lane;                 // q=0 col; q=1 adds 64
  const int b0 = blockIdx.x * GB;
  const size_t gbase = (size_t)b0 * KK * D;

  // ---- P1: write-attn softmax (waves 0..3, wave = batch), fp32 ----
  if (w < 4){
    int flag = g_flag;
    unsigned mbits = 0;
    const int gb = b0 + w;
    if (flag){
      const unsigned char* m8 = (const unsigned char*)maskp;
      #pragma unroll
      for (int k = 0; k < KK; ++k) mbits |= (m8[gb * KK + k] ? 1u : 0u) << k;
    } else {
      const int* m32 = (const int*)maskp;
      #pragma unroll
      for (int k = 0; k < KK; ++k) mbits |= (m32[gb * KK + k] ? 1u : 0u) << k;
    }
    #pragma unroll
    for (int s = 0; s < SS; ++s){
      const float* ap = g_aq + s * D + lane * 8;
      float a0 = ap[0], a1 = ap[1], a2 = ap[2], a3 = ap[3];
      float a4 = ap[4], a5 = ap[5], a6 = ap[6], a7 = ap[7];
      float lg[KK];
      #pragma unroll
      for (int k = 0; k < KK; ++k){
        const float* hp = hidden + gbase + (size_t)(w * KK + k) * D + lane * 8;
        float4 h0 = *(const float4*)hp;
        float4 h1 = *(const float4*)(hp + 4);
        float p = fmaf(a0,h0.x, fmaf(a1,h0.y, fmaf(a2,h0.z, fmaf(a3,h0.w,
                  fmaf(a4,h1.x, fmaf(a5,h1.y, fmaf(a6,h1.z, a7*h1.w)))))));
        p = wred(p) * SCALE;
        lg[k] = ((mbits >> k) & 1u) ? p : -3.0e38f;
      }
      float mx = -3.0e38f;
      #pragma unroll
      for (int k = 0; k < KK; ++k) mx = fmaxf(mx, lg[k]);
      float pe[KK]; float sum = 0.f;
      #pragma unroll
      for (int k = 0; k < KK; ++k){ pe[k] = (lg[k] > -1e38f) ? __expf(lg[k] - mx) : 0.f; sum += pe[k]; }
      float inv = (sum > 0.f) ? 1.f / sum : 0.f;   // all-masked -> zeros (nan_to_num)
      if (lane == 0){
        #pragma unroll
        for (int k = 0; k < KK; ++k) attw[(w * SS + s) * KK + k] = pe[k] * inv;
      }
    }
  }
  __syncthreads();                              // S1: attw ready

  // ---- P2: h_mix = attn_w @ hidden (fp32 acc) -> mixH (bf16) ----
  {
    #pragma unroll
    for (int i = 0; i < 2; ++i){
      int chunk = i * 512 + tid;                // 1024 chunks of 8
      int row = chunk >> 6;                     // 0..15 = bl*4+s
      int c8 = (chunk & 63) * 8;
      int bl = row >> 2, s = row & 3;
      float acc[8] = {0,0,0,0,0,0,0,0};
      #pragma unroll
      for (int k = 0; k < KK; ++k){
        float a = attw[(bl * SS + s) * KK + k];
        const float* hp = hidden + gbase + (size_t)(bl * KK + k) * D + c8;
        float4 h0 = *(const float4*)hp;
        float4 h1 = *(const float4*)(hp + 4);
        acc[0] = fmaf(a,h0.x,acc[0]); acc[1] = fmaf(a,h0.y,acc[1]);
        acc[2] = fmaf(a,h0.z,acc[2]); acc[3] = fmaf(a,h0.w,acc[3]);
        acc[4] = fmaf(a,h1.x,acc[4]); acc[5] = fmaf(a,h1.y,acc[5]);
        acc[6] = fmaf(a,h1.z,acc[6]); acc[7] = fmaf(a,h1.w,acc[7]);
      }
      unsigned d0 = ((unsigned)f2bf(acc[1]) << 16) | f2bf(acc[0]);
      unsigned d1 = ((unsigned)f2bf(acc[3]) << 16) | f2bf(acc[2]);
      unsigned d2 = ((unsigned)f2bf(acc[5]) << 16) | f2bf(acc[4]);
      unsigned d3 = ((unsigned)f2bf(acc[7]) << 16) | f2bf(acc[6]);
      *(uint4*)(mixH + row * ASTRH + c8) = make_uint4(d0, d1, d2, d3);
    }
  }
  __syncthreads();                              // S2: mix ready

  // bf16 GEMM inner loop: acc[8][2] += A[rg*8+r][k] * B[k][col0 + 64q], 64 steps of 8k
#define GEMM16(BMAT, AROWS)                                                  \
    _Pragma("unroll 2")                                                      \
    for (int ks = 0; ks < 64; ++ks){                                         \
      uint4 bA = *(const uint4*)(bp_ + (ks << 12));                          \
      uint4 bB = *(const uint4*)(bp_ + (ks << 12) + 512);                    \
      float bl0[4], bh0[4], bl1[4], bh1[4];                                  \
      { const unsigned* bu = (const unsigned*)&bA;                           \
        _Pragma("unroll") for (int j = 0; j < 4; ++j){                       \
          bl0[j] = __uint_as_float(bu[j] << 16);                             \
          bh0[j] = __uint_as_float(bu[j] & 0xffff0000u); } }                 \
      { const unsigned* bu = (const unsigned*)&bB;                           \
        _Pragma("unroll") for (int j = 0; j < 4; ++j){                       \
          bl1[j] = __uint_as_float(bu[j] << 16);                             \
          bh1[j] = __uint_as_float(bu[j] & 0xffff0000u); } }                 \
      _Pragma("unroll")                                                      \
      for (int r = 0; r < 8; ++r){                                           \
        uint4 aV = *(const uint4*)((AROWS) + r * ASTRH + (ks << 3));         \
        const unsigned* au = (const unsigned*)&aV;                           \
        _Pragma("unroll")                                                    \
        for (int j = 0; j < 4; ++j){                                         \
          float al = __uint_as_float(au[j] << 16);                           \
          float ah = __uint_as_float(au[j] & 0xffff0000u);                   \
          acc[r][0] = fmaf(ah, bh0[j], fmaf(al, bl0[j], acc[r][0]));         \
          acc[r][1] = fmaf(ah, bh1[j], fmaf(al, bl1[j], acc[r][1]));         \
        }                                                                    \
      }                                                                      \
    }

  // ---- GEMM1: x = h_mix @ Wv_w^T + slots; LN -> wsb (ws_upd bf16) ----
  {
    float acc[8][2];
    #pragma unroll
    for (int r = 0; r < 8; ++r){ acc[r][0] = 0.f; acc[r][1] = 0.f; }
    const unsigned short* bp_ = g_bv16 + ((size_t)col0 << 3);
    const unsigned short* arows = mixH + (rg << 3) * ASTRH;
    GEMM16(g_bv16, arows)
    float x[8][2];
    #pragma unroll
    for (int r = 0; r < 8; ++r){
      int row = (rg << 3) + r;
      float v0 = acc[r][0] + slots[(row & 3) * D + col0];
      float v1 = acc[r][1] + slots[(row & 3) * D + col0 + 64];
      x[r][0] = v0; x[r][1] = v1;
      float s1 = wred(v0 + v1);
      float s2 = wred(fmaf(v0, v0, v1 * v1));
      if (lane == 0){ part1[(cg << 4) + row] = s1; part2[(cg << 4) + row] = s2; }
    }
    __syncthreads();                            // S3: partials ready; mixH reads done
    float gv0 = gws[col0], gv1 = gws[col0 + 64];
    float bv0 = bws[col0], bv1 = bws[col0 + 64];
    #pragma unroll
    for (int r = 0; r < 8; ++r){
      int row = (rg << 3) + r;
      float S1 = (part1[row] + part1[16 + row]) + (part1[32 + row] + part1[48 + row]);
      float S2 = (part2[row] + part2[16 + row]) + (part2[32 + row] + part2[48 + row]);
      float mu = S1 * (1.f / D);
      float rs = rsqrtf(S2 * (1.f / D) - mu * mu + LN_EPS);
      wsb[row * ASTRH + col0]      = f2bf((x[r][0] - mu) * rs * gv0 + bv0);
      wsb[row * ASTRH + col0 + 64] = f2bf((x[r][1] - mu) * rs * gv1 + bv1);
    }
  }
  __syncthreads();                              // S4: ws_upd ready

  // ---- GEMM2: t = ws_upd @ (SCALE*Mr)^T -> tb (fp32; SCALE pre-folded) ----
  {
    float acc[8][2];
    #pragma unroll
    for (int r = 0; r < 8; ++r){ acc[r][0] = 0.f; acc[r][1] = 0.f; }
    const unsigned short* bp_ = g_mr16 + ((size_t)col0 << 3);
    const unsigned short* arows = wsb + (rg << 3) * ASTRH;
    GEMM16(g_mr16, arows)
    #pragma unroll
    for (int r = 0; r < 8; ++r){
      int row = (rg << 3) + r;
      tb[row * TSTR + col0]      = acc[r][0];
      tb[row * TSTR + col0 + 64] = acc[r][1];
    }
  }
  __syncthreads();                              // S5: t ready

  // ---- P5: read-attn softmax over s (fp32 hidden x fp32 t) ----
  {
    int bl = w >> 1, kb = (w & 1) * 4;
    #pragma unroll
    for (int kk = 0; kk < 4; ++kk){
      int k = kb + kk;
      const float* hp = hidden + gbase + (size_t)(bl * KK + k) * D + lane * 8;
      float4 h0 = *(const float4*)hp;
      float4 h1 = *(const float4*)(hp + 4);
      float lg[SS];
      #pragma unroll
      for (int s = 0; s < SS; ++s){
        const float* tp = tb + (bl * SS + s) * TSTR + lane * 8;
        float4 t0 = *(const float4*)tp;
        float4 t1 = *(const float4*)(tp + 4);
        float p = fmaf(h0.x,t0.x, fmaf(h0.y,t0.y, fmaf(h0.z,t0.z, fmaf(h0.w,t0.w,
                  fmaf(h1.x,t1.x, fmaf(h1.y,t1.y, fmaf(h1.z,t1.z, h1.w*t1.w)))))));
        lg[s] = wred(p);                        // t already carries SCALE
      }
      float mx = fmaxf(fmaxf(lg[0], lg[1]), fmaxf(lg[2], lg[3]));
      float pe[SS]; float sum = 0.f;
      #pragma unroll
      for (int s = 0; s < SS; ++s){ pe[s] = __expf(lg[s] - mx); sum += pe[s]; }
      float inv = 1.f / sum;
      if (lane == 0){
        #pragma unroll
        for (int s = 0; s < SS; ++s) attr[(bl * KK + k) * SS + s] = pe[s] * inv;
      }
    }
  }
  __syncthreads();                              // S6: t consumed, attr ready

  // ---- GEMM3: v = ws_upd @ Mo^T -> vb (fp32, overwrites t region) ----
  {
    float acc[8][2];
    #pragma unroll
    for (int r = 0; r < 8; ++r){ acc[r][0] = 0.f; acc[r][1] = 0.f; }
    const unsigned short* bp_ = g_mo16 + ((size_t)col0 << 3);
    const unsigned short* arows = wsb + (rg << 3) * ASTRH;
    GEMM16(g_mo16, arows)
    #pragma unroll
    for (int r = 0; r < 8; ++r){
      int row = (rg << 3) + r;
      vb[row * TSTR + col0]      = acc[r][0];
      vb[row * TSTR + col0 + 64] = acc[r][1];
    }
  }
  __syncthreads();                              // S7: v ready

  // ---- P6: out = LN(hidden + sum_s p_s * v_s), fp32 ----
  {
    #pragma unroll
    for (int i = 0; i < 4; ++i){
      int row = w * 4 + i;                      // flat = bl*8+k
      int bl = row >> 3;
      float p0 = attr[row * SS + 0], p1 = attr[row * SS + 1];
      float p2 = attr[row * SS + 2], p3 = attr[row * SS + 3];
      float x[8]; float s1 = 0.f, s2 = 0.f;
      #pragma unroll
      for (int j2 = 0; j2 < 2; ++j2){
        int c2 = j2 * 256 + lane * 4;
        float4 hv = *(const float4*)(hidden + gbase + (size_t)row * D + c2);
        float4 v0 = *(const float4*)(vb + (bl * SS + 0) * TSTR + c2);
        float4 v1 = *(const float4*)(vb + (bl * SS + 1) * TSTR + c2);
        float4 v2 = *(const float4*)(vb + (bl * SS + 2) * TSTR + c2);
        float4 v3 = *(const float4*)(vb + (bl * SS + 3) * TSTR + c2);
        float hx[4] = {hv.x, hv.y, hv.z, hv.w};
        float vx0[4] = {v0.x, v0.y, v0.z, v0.w};
        float vx1[4] = {v1.x, v1.y, v1.z, v1.w};
        float vx2[4] = {v2.x, v2.y, v2.z, v2.w};
        float vx3[4] = {v3.x, v3.y, v3.z, v3.w};
        #pragma unroll
        for (int j = 0; j < 4; ++j){
          float xv = hx[j];
          xv = fmaf(p0, vx0[j], xv);
          xv = fmaf(p1, vx1[j], xv);
          xv = fmaf(p2, vx2[j], xv);
          xv = fmaf(p3, vx3[j], xv);
          x[j2 * 4 + j] = xv; s1 += xv; s2 = fmaf(xv, xv, s2);
        }
      }
      s1 = wred(s1); s2 = wred(s2);
      float mu = s1 * (1.f / D);
      float rs = rsqrtf(s2 * (1.f / D) - mu * mu + LN_EPS);
      #pragma unroll
      for (int j2 = 0; j2 < 2; ++j2){
        int c2 = j2 * 256 + lane * 4;
        float4 g  = *(const float4*)(gout + c2);
        float4 bb = *(const float4*)(bout + c2);
        float4 o;
        o.x = (x[j2*4+0] - mu) * rs * g.x + bb.x;
        o.y = (x[j2*4+1] - mu) * rs * g.y + bb.y;
        o.z = (x[j2*4+2] - mu) * rs * g.z + bb.z;
        o.w = (x[j2*4+3] - mu) * rs * g.w + bb.w;
        *(float4*)(out + gbase + (size_t)row * D + c2) = o;
      }
    }
  }
}

extern "C" void kernel_launch(void* const* d_in, const int* in_sizes, int n_in,
                              void* d_out, int out_size, void* d_ws, size_t ws_size,
                              hipStream_t stream){
  const float* hidden = (const float*)d_in[0];
  const void*  mask   = d_in[1];
  const float* slots  = (const float*)d_in[2];
  const float* wq_w   = (const float*)d_in[3];
  const float* wk_w   = (const float*)d_in[4];
  const float* wv_w   = (const float*)d_in[5];
  const float* wq_r   = (const float*)d_in[6];
  const float* wk_r   = (const float*)d_in[7];
  const float* wv_r   = (const float*)d_in[8];
  const float* wo     = (const float*)d_in[9];
  const float* g_ws_  = (const float*)d_in[10];
  const float* b_ws_  = (const float*)d_in[11];
  const float* g_out_ = (const float*)d_in[12];
  const float* b_out_ = (const float*)d_in[13];

  hipLaunchKernelGGL(kprep, dim3(8, 32, 4), dim3(256), 0, stream,
                     wq_w, wk_w, wq_r, wk_r, wo, wv_r, wv_w);
  hipLaunchKernelGGL(kaq,   dim3(4, 8), dim3(64), 0, stream, slots, mask);

  hipLaunchKernelGGL(k4_main, dim3(BTOT / GB), dim3(512), 0, stream,
                     hidden, mask, slots, g_ws_, b_ws_, g_out_, b_out_, (float*)d_out);
}